// Round 1
// baseline (1887.983 us; speedup 1.0000x reference)
//
#include <hip/hip_runtime.h>
#include <hip/hip_bf16.h>
#include <stdint.h>

#define N_TOK 16384
#define C_DIM 1024
#define E_NUM 8
#define H_DIM 2752
#define CAP   5120
#define NB0   1024   // gating blocks, 16 tokens each

typedef __attribute__((ext_vector_type(8))) short short8;
typedef __attribute__((ext_vector_type(4))) float floatx4;

__device__ __forceinline__ float bf2f(ushort u) {
    union { uint32_t i; float f; } v; v.i = ((uint32_t)u) << 16; return v.f;
}
__device__ __forceinline__ ushort f2bf(float f) {
    union { float f; uint32_t i; } v; v.f = f;
    uint32_t x = v.i;
    uint32_t r = (x + 0x7fffu + ((x >> 16) & 1u)) >> 16;
    return (ushort)r;
}
__device__ __forceinline__ float rnd_bf(float f) { return bf2f(f2bf(f)); }

// direct global->LDS 16B DMA. LDS dest is wave-uniform base + lane*16 (linear);
// global source is per-lane (enables row gather + source-side swizzle).
typedef __attribute__((address_space(3))) ushort lds_ushort;
typedef const __attribute__((address_space(1))) ushort glb_ushort;
__device__ __forceinline__ void async16(const ushort* g, ushort* l) {
    __builtin_amdgcn_global_load_lds((glb_ushort*)g, (lds_ushort*)l, 16, 0, 0);
}

// ---------------- dtype sniffer ----------------
// Low 16 bits of each dword: for genuine bf16 data it's a real bf16 value
// (exp in [96,144] for ~N(0,sigma) data); for f32 data it's mantissa bits
// (exp field uniform -> ~19% hit rate). flags[i]=1 => bf16.
__global__ void k_sniff(const uint32_t* __restrict__ x, const uint32_t* __restrict__ gw,
                        const uint32_t* __restrict__ wg, const uint32_t* __restrict__ wu,
                        const uint32_t* __restrict__ wd, int* __restrict__ flags) {
    __shared__ int cnt;
    const uint32_t* ptrs[5] = {x, gw, wg, wu, wd};
    const int ndw[5] = {8388608, 4096, 11272192, 11272192, 11272192}; // dword count if bf16
    for (int i = 0; i < 5; ++i) {
        if (threadIdx.x == 0) cnt = 0;
        __syncthreads();
        int stride = ndw[i] / 2048; if (stride < 1) stride = 1;
        int hits = 0;
        for (int s = threadIdx.x; s < 2048; s += 256) {
            uint32_t w = ptrs[i][(size_t)s * stride];
            uint32_t lo = w & 0xFFFFu;
            uint32_t e = (lo >> 7) & 0xFFu;
            if (lo == 0u || (e >= 96u && e <= 144u)) hits++;
        }
        atomicAdd(&cnt, hits);
        __syncthreads();
        if (threadIdx.x == 0) flags[i] = (cnt >= 1229) ? 1 : 0;  // 60%
        __syncthreads();
    }
}

// ---------------- zero out + stats ----------------
__global__ void k_zero(uint32_t* __restrict__ outw, const int* __restrict__ flags,
                       float* __restrict__ stats, int out_size) {
    int obf = flags[0];
    size_t bytes = (size_t)out_size * (obf ? 2 : 4);
    size_t ndw = bytes >> 2;
    for (size_t i = (size_t)blockIdx.x * 256 + threadIdx.x; i < ndw;
         i += (size_t)gridDim.x * 256)
        outw[i] = 0u;
    if (blockIdx.x == 0 && threadIdx.x < 16) stats[threadIdx.x] = 0.f;
}

// ---------------- x -> bf16 workspace copy (uniform GEMM A input) ----------------
__global__ __launch_bounds__(256) void k_xcast(const void* __restrict__ x_,
                                               const int* __restrict__ flags,
                                               ushort* __restrict__ xbf) {
    int fx = flags[0];
    size_t nv = (size_t)N_TOK * C_DIM / 8;
    for (size_t i = (size_t)blockIdx.x * 256 + threadIdx.x; i < nv;
         i += (size_t)gridDim.x * 256) {
        size_t e = i * 8;
        if (fx) {
            *(uint4*)(xbf + e) = *(const uint4*)((const ushort*)x_ + e);
        } else {
            const float* xp = (const float*)x_ + e;
            float4 a0 = *(const float4*)xp;
            float4 a1 = *(const float4*)(xp + 4);
            uint4 v;
            ushort* u = (ushort*)&v;
            u[0]=f2bf(a0.x); u[1]=f2bf(a0.y); u[2]=f2bf(a0.z); u[3]=f2bf(a0.w);
            u[4]=f2bf(a1.x); u[5]=f2bf(a1.y); u[6]=f2bf(a1.z); u[7]=f2bf(a1.w);
            *(uint4*)(xbf + e) = v;
        }
    }
}

// ---------------- gating ----------------
__global__ __launch_bounds__(256) void k_gate(const void* __restrict__ x_,
                                              const void* __restrict__ gw_,
                                              const int* __restrict__ flags,
                                              int* __restrict__ top2i,
                                              float* __restrict__ top2v,
                                              int* __restrict__ blkcnt,
                                              float* __restrict__ stats) {
    __shared__ float gwt[8192];     // [e][c] transposed, f32
    __shared__ float sh_me[8];
    __shared__ float sh_z;
    __shared__ int   sh_cnt[16];    // [k][e]
    int fx = flags[0], fg = flags[1];
    int tid = threadIdx.x;
    if (fg) {
        const ushort* g16 = (const ushort*)gw_;
        for (int i = tid; i < 8192; i += 256)
            gwt[(i & 7) * 1024 + (i >> 3)] = bf2f(g16[i]);
    } else {
        const float* g32 = (const float*)gw_;
        for (int i = tid; i < 8192; i += 256)
            gwt[(i & 7) * 1024 + (i >> 3)] = g32[i];
    }
    if (tid < 8) sh_me[tid] = 0.f;
    if (tid == 8) sh_z = 0.f;
    if (tid < 16) sh_cnt[tid] = 0;
    __syncthreads();
    int wv = tid >> 6, lane = tid & 63;
    const ushort* x16 = (const ushort*)x_;
    const float*  x32 = (const float*)x_;
    for (int it = 0; it < 4; ++it) {
        int t = blockIdx.x * 16 + wv * 4 + it;
        size_t xrow = (size_t)t * C_DIM;
        float acc[8] = {0.f,0.f,0.f,0.f,0.f,0.f,0.f,0.f};
        if (fx) {
            for (int j = 0; j < 16; ++j) {
                int c = j * 64 + lane;
                float xv = bf2f(x16[xrow + c]);
                #pragma unroll
                for (int e = 0; e < 8; ++e) acc[e] += xv * gwt[e * 1024 + c];
            }
        } else {
            for (int j = 0; j < 16; ++j) {
                int c = j * 64 + lane;
                float xv = x32[xrow + c];
                #pragma unroll
                for (int e = 0; e < 8; ++e) acc[e] += xv * gwt[e * 1024 + c];
            }
        }
        #pragma unroll
        for (int off = 32; off > 0; off >>= 1) {
            #pragma unroll
            for (int e = 0; e < 8; ++e) acc[e] += __shfl_xor(acc[e], off, 64);
        }
        // all lanes uniform now
        float lb[8];
        if (fx) {
            #pragma unroll
            for (int e = 0; e < 8; ++e) lb[e] = rnd_bf(acc[e]); // bf16 matmul output
        } else {
            #pragma unroll
            for (int e = 0; e < 8; ++e) lb[e] = acc[e];
        }
        float mx = lb[0];
        #pragma unroll
        for (int e = 1; e < 8; ++e) mx = fmaxf(mx, lb[e]);
        float p[8]; float s = 0.f, zsq = 0.f;
        #pragma unroll
        for (int e = 0; e < 8; ++e) {
            zsq += lb[e] * lb[e];
            p[e] = expf(lb[e] - mx);
            s += p[e];
        }
        float inv = 1.f / s;
        float gate[8];
        if (fx) {
            #pragma unroll
            for (int e = 0; e < 8; ++e) gate[e] = rnd_bf(p[e] * inv);
        } else {
            #pragma unroll
            for (int e = 0; e < 8; ++e) gate[e] = p[e] * inv;
        }
        int i1 = 0;
        #pragma unroll
        for (int e = 1; e < 8; ++e) if (gate[e] > gate[i1]) i1 = e;
        int i2 = (i1 == 0) ? 1 : 0;
        #pragma unroll
        for (int e = 0; e < 8; ++e) if (e != i1 && gate[e] > gate[i2]) i2 = e;
        if (lane == 0) {
            top2i[t * 2] = i1; top2i[t * 2 + 1] = i2;
            top2v[t * 2] = gate[i1]; top2v[t * 2 + 1] = gate[i2];
            atomicAdd(&sh_z, zsq);
            atomicAdd(&sh_cnt[i1], 1);
            atomicAdd(&sh_cnt[8 + i2], 1);
        }
        if (lane < 8) atomicAdd(&sh_me[lane], gate[lane]);
    }
    __syncthreads();
    if (tid < 16) blkcnt[blockIdx.x * 16 + tid] = sh_cnt[tid];
    if (tid < 8) atomicAdd(&stats[tid], sh_me[tid]);
    if (tid == 8) atomicAdd(&stats[8], sh_z);
}

// ---------------- scan + losses ----------------
__global__ __launch_bounds__(256) void k_scan(const int* __restrict__ blkcnt,
                                              int* __restrict__ blkoff,
                                              int* __restrict__ meta,
                                              const float* __restrict__ stats,
                                              const int* __restrict__ flags,
                                              char* __restrict__ outc,
                                              int tailoff) {
    __shared__ int part[16][16];
    __shared__ int segbase[16][16];
    __shared__ int tot[16];
    int tid = threadIdx.x;
    int pair = tid & 15, seg = tid >> 4;
    int s = 0;
    for (int b = seg * 64; b < seg * 64 + 64; ++b) s += blkcnt[b * 16 + pair];
    part[seg][pair] = s;
    __syncthreads();
    if (tid < 16) {
        int run = 0;
        for (int g = 0; g < 16; ++g) { segbase[g][tid] = run; run += part[g][tid]; }
        tot[tid] = run;
    }
    __syncthreads();
    int run = segbase[seg][pair];
    for (int b = seg * 64; b < seg * 64 + 64; ++b) {
        blkoff[b * 16 + pair] = run;
        run += blkcnt[b * 16 + pair];
    }
    if (tid == 0) {
        int obf = flags[0];
        int basev = 0;
        float aux;
        if (obf) {
            float s_bf = 0.f;
            for (int e = 0; e < 8; ++e) {
                int t0 = tot[e], t1 = tot[8 + e];
                int k0 = t0 < CAP ? t0 : CAP;
                int k1 = t1 < CAP ? t1 : CAP;
                meta[e] = basev; meta[8 + e] = k0; meta[16 + e] = k0 + k1;
                basev += k0 + k1;
                float me_b = rnd_bf(stats[e] / (float)N_TOK);
                // bf16 scatter-add of 2^-14 sticks at 2^-6 (tie-to-even): sat 256
                int cnt = t0 < 256 ? t0 : 256;
                float ce = (float)cnt * (1.f / 16384.f);
                s_bf = rnd_bf(s_bf + rnd_bf(me_b * ce));
            }
            aux = 8.f * s_bf;
        } else {
            float sf = 0.f;
            for (int e = 0; e < 8; ++e) {
                int t0 = tot[e], t1 = tot[8 + e];
                int k0 = t0 < CAP ? t0 : CAP;
                int k1 = t1 < CAP ? t1 : CAP;
                meta[e] = basev; meta[8 + e] = k0; meta[16 + e] = k0 + k1;
                basev += k0 + k1;
                sf += (stats[e] / (float)N_TOK) * ((float)t0 / (float)N_TOK);
            }
            aux = 8.f * sf;
        }
        float z = stats[8] / (float)(N_TOK * 8);
        if (obf) {
            ushort* tl = (ushort*)(outc + (size_t)tailoff * 2);
            tl[0] = f2bf(aux); tl[1] = f2bf(z);
        } else {
            float* tl = (float*)(outc + (size_t)tailoff * 4);
            tl[0] = aux; tl[1] = z;
        }
    }
}

// ---------------- build compact lists ----------------
__global__ __launch_bounds__(64) void k_build(const int* __restrict__ top2i,
                                              const int* __restrict__ blkoff,
                                              const int* __restrict__ meta,
                                              int* __restrict__ listtok) {
    __shared__ int sidx[32];
    int b = blockIdx.x, tid = threadIdx.x;
    if (tid < 32) sidx[tid] = top2i[b * 32 + tid];
    __syncthreads();
    if (tid < 16) {
        int t = b * 16 + tid;
        #pragma unroll
        for (int k = 0; k < 2; ++k) {
            int e = sidx[tid * 2 + k];
            int rank = 0;
            for (int i = 0; i < tid; ++i) if (sidx[i * 2 + k] == e) rank++;
            int pos = blkoff[b * 16 + k * 8 + e] + rank;
            if (pos < CAP) {
                int row = meta[e] + (k ? meta[8 + e] : 0) + pos;
                listtok[row] = t;
            }
        }
    }
}

// ---- per-expert convert+transpose: z=0 Wg, z=1 Wu (CxH), z=2 Wd (HxC) -> bf16 [Cc][R] ----
__global__ __launch_bounds__(256) void k_transpose_e(const void* __restrict__ Wg,
                                                     const void* __restrict__ Wu,
                                                     const void* __restrict__ Wd,
                                                     ushort* __restrict__ tG,
                                                     ushort* __restrict__ tU,
                                                     ushort* __restrict__ tD,
                                                     const int* __restrict__ flags,
                                                     int e) {
    __shared__ ushort tile[32][33];
    int z = blockIdx.z;
    int fbf = flags[2 + z];
    const void* src = (z == 0) ? Wg : ((z == 1) ? Wu : Wd);
    ushort* outp = (z == 0) ? tG : ((z == 1) ? tU : tD);
    int R = (z == 2) ? H_DIM : C_DIM, Cc = (z == 2) ? C_DIM : H_DIM;
    size_t woff = (size_t)e * C_DIM * H_DIM;
    int c0 = blockIdx.x * 32, r0 = blockIdx.y * 32;
    if (c0 >= Cc || r0 >= R) return;
    int tx = threadIdx.x, ty = threadIdx.y;  // 32 x 8
    #pragma unroll
    for (int i = 0; i < 4; ++i) {
        int r = r0 + ty + i * 8, c = c0 + tx;
        ushort v = 0;
        if (r < R && c < Cc) {
            size_t idx = woff + (size_t)r * Cc + c;
            v = fbf ? ((const ushort*)src)[idx] : f2bf(((const float*)src)[idx]);
        }
        tile[ty + i * 8][tx] = v;
    }
    __syncthreads();
    #pragma unroll
    for (int i = 0; i < 4; ++i) {
        int c = c0 + ty + i * 8, r = r0 + tx;
        if (c < Cc && r < R) outp[(size_t)c * R + r] = tile[tx][ty + i * 8];
    }
}

// ---------------- fused gate+up GEMM (one expert, one m-chunk) ----------------
// m97 structure: global_load_lds width-16 staging, linear LDS (stride 32 bf16)
// with both-sides 16B XOR swizzle: slot = seg ^ ((row>>1)&3).
__global__ __launch_bounds__(256) void k_gateup(const ushort* __restrict__ xbf,
                                                const ushort* __restrict__ Wgt,
                                                const ushort* __restrict__ Wut,
                                                const int* __restrict__ meta,
                                                const int* __restrict__ listtok,
                                                const int* __restrict__ flags,
                                                ushort* __restrict__ act,
                                                int ex, int mbase) {
    int Me = meta[16 + ex];
    int mloc = blockIdx.y * 64;           // chunk-local
    int m0 = mbase + mloc;                // expert-local
    if (m0 >= Me) return;
    int base = meta[ex];
    int h0 = blockIdx.x * 128;
    int fx = flags[0];

    __shared__ __align__(16) ushort sA[64 * 32];
    __shared__ __align__(16) ushort sG[128 * 32];
    __shared__ __align__(16) ushort sU[128 * 32];

    int tid = threadIdx.x;
    int lane = tid & 63, wv = tid >> 6;

    // staging: lane -> (row-in-group = lane>>2, slot = lane&3); the data placed
    // at slot s of row r must be logical segment s^((r>>1)&3); group bases are
    // multiples of 16 rows so (r>>1)&3 == ((lane>>2)>>1)&3 == (lane>>3)&3.
    int sseg = (lane & 3) ^ ((lane >> 3) & 3);
    int ra = lane >> 2;

    // A: wave wv stages rows wv*16 .. wv*16+15 (gathered token rows, clamped)
    int arow = wv * 16 + ra;
    int trow = m0 + arow; if (trow >= Me) trow = Me - 1;   // OOB -> dup last row (masked at write)
    const ushort* gA = xbf + (size_t)listtok[base + trow] * C_DIM + sseg * 8;
    ushort* lA = &sA[(wv * 16) * 32];

    // G/U: wave wv stages rows wv*32 .. wv*32+31 in two 16-row instructions
    int hr0 = h0 + wv * 32 + ra;
    int hc0 = hr0 < H_DIM ? hr0 : H_DIM - 1;               // OOB -> clamp (masked at write)
    int hc1 = (hr0 + 16) < H_DIM ? (hr0 + 16) : H_DIM - 1;
    const ushort* gG0 = Wgt + (size_t)hc0 * C_DIM + sseg * 8;
    const ushort* gG1 = Wgt + (size_t)hc1 * C_DIM + sseg * 8;
    const ushort* gU0 = Wut + (size_t)hc0 * C_DIM + sseg * 8;
    const ushort* gU1 = Wut + (size_t)hc1 * C_DIM + sseg * 8;
    ushort* lG = &sG[(wv * 32) * 32];
    ushort* lU = &sU[(wv * 32) * 32];

    int lrow = lane & 15, quad = lane >> 4;
    // read-side swizzle: same involution; row bases are multiples of 16 so only lrow matters
    int rslot = (quad ^ ((lrow >> 1) & 3)) * 8;

    floatx4 zf = {0.f, 0.f, 0.f, 0.f};
    floatx4 accG[4][2], accU[4][2];
    #pragma unroll
    for (int i = 0; i < 4; ++i)
        #pragma unroll
        for (int j = 0; j < 2; ++j) { accG[i][j] = zf; accU[i][j] = zf; }

    for (int kk = 0; kk < C_DIM; kk += 32) {
        async16(gA + kk, lA);
        async16(gG0 + kk, lG);
        async16(gG1 + kk, lG + 16 * 32);
        async16(gU0 + kk, lU);
        async16(gU1 + kk, lU + 16 * 32);
        __syncthreads();   // implicit vmcnt(0) drain -> LDS tile ready
        short8 a[4], gfr[2], ufr[2];
        #pragma unroll
        for (int rt = 0; rt < 4; ++rt)
            a[rt] = *(const short8*)&sA[(rt * 16 + lrow) * 32 + rslot];
        #pragma unroll
        for (int j = 0; j < 2; ++j) {
            int n = wv * 32 + j * 16 + lrow;
            gfr[j] = *(const short8*)&sG[n * 32 + rslot];
            ufr[j] = *(const short8*)&sU[n * 32 + rslot];
        }
        #pragma unroll
        for (int rt = 0; rt < 4; ++rt)
            #pragma unroll
            for (int j = 0; j < 2; ++j) {
                accG[rt][j] = __builtin_amdgcn_mfma_f32_16x16x32_bf16(a[rt], gfr[j], accG[rt][j], 0, 0, 0);
                accU[rt][j] = __builtin_amdgcn_mfma_f32_16x16x32_bf16(a[rt], ufr[j], accU[rt][j], 0, 0, 0);
            }
        __syncthreads();   // guard LDS overwrite by next K-step
    }
    #pragma unroll
    for (int rt = 0; rt < 4; ++rt)
        #pragma unroll
        for (int j = 0; j < 2; ++j)
            #pragma unroll
            for (int r = 0; r < 4; ++r) {
                int m = m0 + rt * 16 + quad * 4 + r;
                int hh = h0 + wv * 32 + j * 16 + lrow;
                if (m < Me && hh < H_DIM) {
                    float g = accG[rt][j][r];
                    float uu = accU[rt][j][r];
                    float res;
                    if (fx) {
                        float gb = rnd_bf(g), ub = rnd_bf(uu);
                        res = rnd_bf(gb / (1.f + __expf(-gb))) * ub;
                    } else {
                        res = (g / (1.f + __expf(-g))) * uu;
                    }
                    act[(size_t)(mloc + rt * 16 + quad * 4 + r) * H_DIM + hh] = f2bf(res);
                }
            }
}

// ---------------- down GEMM + scatter-combine ----------------
__global__ __launch_bounds__(256) void k_down(const ushort* __restrict__ act,
                                              const ushort* __restrict__ Wdt,
                                              const int* __restrict__ meta,
                                              const int* __restrict__ listtok,
                                              const float* __restrict__ top2v,
                                              const int* __restrict__ flags,
                                              char* __restrict__ outc,
                                              int ex, int mbase) {
    int Me = meta[16 + ex];
    int mloc = blockIdx.y * 64;
    int m0 = mbase + mloc;
    if (m0 >= Me) return;
    int base = meta[ex];
    int k0cnt = meta[8 + ex];
    int c0 = blockIdx.x * 128;
    int obf = flags[0];

    __shared__ __align__(16) ushort sA[64 * 32];
    __shared__ __align__(16) ushort sB[128 * 32];

    int tid = threadIdx.x;
    int lane = tid & 63, wv = tid >> 6;

    int sseg = (lane & 3) ^ ((lane >> 3) & 3);
    int ra = lane >> 2;

    // A rows: chunk-local act rows (OOB rows hold garbage; masked at write)
    const ushort* gA = act + (size_t)(mloc + wv * 16 + ra) * H_DIM + sseg * 8;
    ushort* lA = &sA[(wv * 16) * 32];

    // B rows: c0..c0+127 (C_DIM divisible by 128, no clamp needed)
    const ushort* gB0 = Wdt + (size_t)(c0 + wv * 32 + ra) * H_DIM + sseg * 8;
    const ushort* gB1 = Wdt + (size_t)(c0 + wv * 32 + 16 + ra) * H_DIM + sseg * 8;
    ushort* lB = &sB[(wv * 32) * 32];

    int lrow = lane & 15, quad = lane >> 4;
    int rslot = (quad ^ ((lrow >> 1) & 3)) * 8;

    floatx4 zf = {0.f, 0.f, 0.f, 0.f};
    floatx4 acc[4][2];
    #pragma unroll
    for (int i = 0; i < 4; ++i)
        #pragma unroll
        for (int j = 0; j < 2; ++j) acc[i][j] = zf;

    for (int kk = 0; kk < H_DIM; kk += 32) {
        async16(gA + kk, lA);
        async16(gB0 + kk, lB);
        async16(gB1 + kk, lB + 16 * 32);
        __syncthreads();
        short8 a[4], b[2];
        #pragma unroll
        for (int rt = 0; rt < 4; ++rt)
            a[rt] = *(const short8*)&sA[(rt * 16 + lrow) * 32 + rslot];
        #pragma unroll
        for (int j = 0; j < 2; ++j)
            b[j] = *(const short8*)&sB[(wv * 32 + j * 16 + lrow) * 32 + rslot];
        #pragma unroll
        for (int rt = 0; rt < 4; ++rt)
            #pragma unroll
            for (int j = 0; j < 2; ++j)
                acc[rt][j] = __builtin_amdgcn_mfma_f32_16x16x32_bf16(a[rt], b[j], acc[rt][j], 0, 0, 0);
        __syncthreads();
    }
    #pragma unroll
    for (int rt = 0; rt < 4; ++rt)
        #pragma unroll
        for (int j = 0; j < 2; ++j)
            #pragma unroll
            for (int r = 0; r < 4; ++r) {
                int m = m0 + rt * 16 + quad * 4 + r;   // expert-local row
                if (m < Me) {
                    int t = listtok[base + m];
                    int k = (m >= k0cnt) ? 1 : 0;
                    float w = top2v[t * 2 + k];
                    int cc = c0 + wv * 32 + j * 16 + lrow;
                    float y = acc[rt][j][r];
                    size_t oidx = (size_t)t * C_DIM + cc;
                    if (obf) {
                        ushort contrib = f2bf(w * rnd_bf(y));  // bf16 product chain
                        uint32_t* word = (uint32_t*)outc + (oidx >> 1);
                        int hi = (int)(oidx & 1);
                        uint32_t old = *word, assumed;
                        do {
                            assumed = old;
                            ushort cur = hi ? (ushort)(assumed >> 16) : (ushort)(assumed & 0xFFFFu);
                            ushort nw = f2bf(bf2f(cur) + bf2f(contrib));
                            uint32_t repl = hi ? ((assumed & 0xFFFFu) | ((uint32_t)nw << 16))
                                               : ((assumed & 0xFFFF0000u) | (uint32_t)nw);
                            if (repl == assumed) break;
                            old = atomicCAS(word, assumed, repl);
                        } while (old != assumed);
                    } else {
                        atomicAdd((float*)outc + oidx, w * y);
                    }
                }
            }
}

extern "C" void kernel_launch(void* const* d_in, const int* in_sizes, int n_in,
                              void* d_out, int out_size, void* d_ws, size_t ws_size,
                              hipStream_t stream) {
    const void* x  = d_in[0];
    const void* gw = d_in[1];
    const void* Wg = d_in[2];
    const void* Wu = d_in[3];
    const void* Wd = d_in[4];
    char* outc = (char*)d_out;

    char* ws = (char*)d_ws;
    size_t off = 0;
    auto alloc = [&](size_t bytes) -> char* {
        char* p = ws + off;
        off += (bytes + 255) & ~(size_t)255;
        return p;
    };
    int*    flags   = (int*)alloc(64);
    float*  stats   = (float*)alloc(64);
    int*    top2i   = (int*)alloc((size_t)N_TOK * 2 * 4);
    float*  top2v   = (float*)alloc((size_t)N_TOK * 2 * 4);
    int*    blkcnt  = (int*)alloc((size_t)NB0 * 16 * 4);
    int*    blkoff  = (int*)alloc((size_t)NB0 * 16 * 4);
    int*    meta    = (int*)alloc(256);
    int*    listtok = (int*)alloc((size_t)N_TOK * 2 * 4);
    ushort* xbf     = (ushort*)alloc((size_t)N_TOK * C_DIM * 2);
    ushort* tG      = (ushort*)alloc((size_t)C_DIM * H_DIM * 2);
    ushort* tU      = (ushort*)alloc((size_t)C_DIM * H_DIM * 2);
    ushort* tD      = (ushort*)alloc((size_t)C_DIM * H_DIM * 2);
    // adaptive act chunk from remaining ws
    size_t rowB = (size_t)H_DIM * 2;
    size_t avail = (ws_size > off + (1 << 20)) ? (ws_size - off - (1 << 20)) : rowB * 64;
    int CH = (int)(avail / rowB);
    if (CH > 2 * CAP) CH = 2 * CAP;
    CH &= ~63;
    if (CH < 64) CH = 64;
    int nch = (2 * CAP + CH - 1) / CH;
    ushort* act = (ushort*)alloc((size_t)CH * rowB);

    k_sniff<<<1, 256, 0, stream>>>((const uint32_t*)x, (const uint32_t*)gw,
                                   (const uint32_t*)Wg, (const uint32_t*)Wu,
                                   (const uint32_t*)Wd, flags);
    k_zero<<<2048, 256, 0, stream>>>((uint32_t*)d_out, flags, stats, out_size);
    k_xcast<<<2048, 256, 0, stream>>>(x, flags, xbf);
    k_gate<<<NB0, 256, 0, stream>>>(x, gw, flags, top2i, top2v, blkcnt, stats);
    k_scan<<<1, 256, 0, stream>>>(blkcnt, blkoff, meta, stats, flags, outc, out_size - 2);
    k_build<<<NB0, 64, 0, stream>>>(top2i, blkoff, meta, listtok);

    dim3 tb(32, 8);
    for (int e = 0; e < E_NUM; ++e) {
        k_transpose_e<<<dim3(86, 86, 3), tb, 0, stream>>>(Wg, Wu, Wd, tG, tU, tD, flags, e);
        for (int c = 0; c < nch; ++c) {
            k_gateup<<<dim3((H_DIM + 127) / 128, CH / 64), 256, 0, stream>>>(
                xbf, tG, tU, meta, listtok, flags, act, e, c * CH);
            k_down<<<dim3(C_DIM / 128, CH / 64), 256, 0, stream>>>(
                act, tD, meta, listtok, top2v, flags, outc, e, c * CH);
        }
    }
}

// Round 2
// 1660.116 us; speedup vs baseline: 1.1373x; 1.1373x over previous
//
#include <hip/hip_runtime.h>
#include <hip/hip_bf16.h>
#include <stdint.h>

#define N_TOK 16384
#define C_DIM 1024
#define E_NUM 8
#define H_DIM 2752
#define CAP   5120
#define NB0   1024   // gating blocks, 16 tokens each
#define GTOT  33280  // worst-case padded global rows (32768 + 8*63, rounded to 64)

typedef __attribute__((ext_vector_type(8))) short short8;
typedef __attribute__((ext_vector_type(4))) float floatx4;

__device__ __forceinline__ float bf2f(ushort u) {
    union { uint32_t i; float f; } v; v.i = ((uint32_t)u) << 16; return v.f;
}
__device__ __forceinline__ ushort f2bf(float f) {
    union { float f; uint32_t i; } v; v.f = f;
    uint32_t x = v.i;
    uint32_t r = (x + 0x7fffu + ((x >> 16) & 1u)) >> 16;
    return (ushort)r;
}
__device__ __forceinline__ float rnd_bf(float f) { return bf2f(f2bf(f)); }

// direct global->LDS 16B DMA. LDS dest is wave-uniform base + lane*16 (linear);
// global source is per-lane (enables row gather + source-side swizzle).
typedef __attribute__((address_space(3))) ushort lds_ushort;
typedef const __attribute__((address_space(1))) ushort glb_ushort;
__device__ __forceinline__ void async16(const ushort* g, ushort* l) {
    __builtin_amdgcn_global_load_lds((glb_ushort*)g, (lds_ushort*)l, 16, 0, 0);
}

// expert whose padded region contains global row 'grow' (meta[0..7] = padded bases, ascending)
__device__ __forceinline__ int expert_of(const int* __restrict__ meta, int grow) {
    int e = 0;
    #pragma unroll
    for (int i = 1; i < 8; ++i) e = (grow >= meta[i]) ? i : e;
    return e;
}

// ---------------- dtype sniffer ----------------
__global__ void k_sniff(const uint32_t* __restrict__ x, const uint32_t* __restrict__ gw,
                        const uint32_t* __restrict__ wg, const uint32_t* __restrict__ wu,
                        const uint32_t* __restrict__ wd, int* __restrict__ flags) {
    __shared__ int cnt;
    const uint32_t* ptrs[5] = {x, gw, wg, wu, wd};
    const int ndw[5] = {8388608, 4096, 11272192, 11272192, 11272192}; // dword count if bf16
    for (int i = 0; i < 5; ++i) {
        if (threadIdx.x == 0) cnt = 0;
        __syncthreads();
        int stride = ndw[i] / 2048; if (stride < 1) stride = 1;
        int hits = 0;
        for (int s = threadIdx.x; s < 2048; s += 256) {
            uint32_t w = ptrs[i][(size_t)s * stride];
            uint32_t lo = w & 0xFFFFu;
            uint32_t e = (lo >> 7) & 0xFFu;
            if (lo == 0u || (e >= 96u && e <= 144u)) hits++;
        }
        atomicAdd(&cnt, hits);
        __syncthreads();
        if (threadIdx.x == 0) flags[i] = (cnt >= 1229) ? 1 : 0;  // 60%
        __syncthreads();
    }
}

// ---------------- zero out + stats ----------------
__global__ void k_zero(uint32_t* __restrict__ outw, const int* __restrict__ flags,
                       float* __restrict__ stats, int out_size) {
    int obf = flags[0];
    size_t bytes = (size_t)out_size * (obf ? 2 : 4);
    size_t ndw = bytes >> 2;
    for (size_t i = (size_t)blockIdx.x * 256 + threadIdx.x; i < ndw;
         i += (size_t)gridDim.x * 256)
        outw[i] = 0u;
    if (blockIdx.x == 0 && threadIdx.x < 16) stats[threadIdx.x] = 0.f;
}

// ---------------- x -> bf16 workspace copy (uniform GEMM A input) ----------------
__global__ __launch_bounds__(256) void k_xcast(const void* __restrict__ x_,
                                               const int* __restrict__ flags,
                                               ushort* __restrict__ xbf) {
    int fx = flags[0];
    size_t nv = (size_t)N_TOK * C_DIM / 8;
    for (size_t i = (size_t)blockIdx.x * 256 + threadIdx.x; i < nv;
         i += (size_t)gridDim.x * 256) {
        size_t e = i * 8;
        if (fx) {
            *(uint4*)(xbf + e) = *(const uint4*)((const ushort*)x_ + e);
        } else {
            const float* xp = (const float*)x_ + e;
            float4 a0 = *(const float4*)xp;
            float4 a1 = *(const float4*)(xp + 4);
            uint4 v;
            ushort* u = (ushort*)&v;
            u[0]=f2bf(a0.x); u[1]=f2bf(a0.y); u[2]=f2bf(a0.z); u[3]=f2bf(a0.w);
            u[4]=f2bf(a1.x); u[5]=f2bf(a1.y); u[6]=f2bf(a1.z); u[7]=f2bf(a1.w);
            *(uint4*)(xbf + e) = v;
        }
    }
}

// ---------------- gating ----------------
__global__ __launch_bounds__(256) void k_gate(const void* __restrict__ x_,
                                              const void* __restrict__ gw_,
                                              const int* __restrict__ flags,
                                              int* __restrict__ top2i,
                                              float* __restrict__ top2v,
                                              int* __restrict__ blkcnt,
                                              float* __restrict__ stats) {
    __shared__ float gwt[8192];     // [e][c] transposed, f32
    __shared__ float sh_me[8];
    __shared__ float sh_z;
    __shared__ int   sh_cnt[16];    // [k][e]
    int fx = flags[0], fg = flags[1];
    int tid = threadIdx.x;
    if (fg) {
        const ushort* g16 = (const ushort*)gw_;
        for (int i = tid; i < 8192; i += 256)
            gwt[(i & 7) * 1024 + (i >> 3)] = bf2f(g16[i]);
    } else {
        const float* g32 = (const float*)gw_;
        for (int i = tid; i < 8192; i += 256)
            gwt[(i & 7) * 1024 + (i >> 3)] = g32[i];
    }
    if (tid < 8) sh_me[tid] = 0.f;
    if (tid == 8) sh_z = 0.f;
    if (tid < 16) sh_cnt[tid] = 0;
    __syncthreads();
    int wv = tid >> 6, lane = tid & 63;
    const ushort* x16 = (const ushort*)x_;
    const float*  x32 = (const float*)x_;
    for (int it = 0; it < 4; ++it) {
        int t = blockIdx.x * 16 + wv * 4 + it;
        size_t xrow = (size_t)t * C_DIM;
        float acc[8] = {0.f,0.f,0.f,0.f,0.f,0.f,0.f,0.f};
        if (fx) {
            for (int j = 0; j < 16; ++j) {
                int c = j * 64 + lane;
                float xv = bf2f(x16[xrow + c]);
                #pragma unroll
                for (int e = 0; e < 8; ++e) acc[e] += xv * gwt[e * 1024 + c];
            }
        } else {
            for (int j = 0; j < 16; ++j) {
                int c = j * 64 + lane;
                float xv = x32[xrow + c];
                #pragma unroll
                for (int e = 0; e < 8; ++e) acc[e] += xv * gwt[e * 1024 + c];
            }
        }
        #pragma unroll
        for (int off = 32; off > 0; off >>= 1) {
            #pragma unroll
            for (int e = 0; e < 8; ++e) acc[e] += __shfl_xor(acc[e], off, 64);
        }
        float lb[8];
        if (fx) {
            #pragma unroll
            for (int e = 0; e < 8; ++e) lb[e] = rnd_bf(acc[e]);
        } else {
            #pragma unroll
            for (int e = 0; e < 8; ++e) lb[e] = acc[e];
        }
        float mx = lb[0];
        #pragma unroll
        for (int e = 1; e < 8; ++e) mx = fmaxf(mx, lb[e]);
        float p[8]; float s = 0.f, zsq = 0.f;
        #pragma unroll
        for (int e = 0; e < 8; ++e) {
            zsq += lb[e] * lb[e];
            p[e] = expf(lb[e] - mx);
            s += p[e];
        }
        float inv = 1.f / s;
        float gate[8];
        if (fx) {
            #pragma unroll
            for (int e = 0; e < 8; ++e) gate[e] = rnd_bf(p[e] * inv);
        } else {
            #pragma unroll
            for (int e = 0; e < 8; ++e) gate[e] = p[e] * inv;
        }
        int i1 = 0;
        #pragma unroll
        for (int e = 1; e < 8; ++e) if (gate[e] > gate[i1]) i1 = e;
        int i2 = (i1 == 0) ? 1 : 0;
        #pragma unroll
        for (int e = 0; e < 8; ++e) if (e != i1 && gate[e] > gate[i2]) i2 = e;
        if (lane == 0) {
            top2i[t * 2] = i1; top2i[t * 2 + 1] = i2;
            top2v[t * 2] = gate[i1]; top2v[t * 2 + 1] = gate[i2];
            atomicAdd(&sh_z, zsq);
            atomicAdd(&sh_cnt[i1], 1);
            atomicAdd(&sh_cnt[8 + i2], 1);
        }
        if (lane < 8) atomicAdd(&sh_me[lane], gate[lane]);
    }
    __syncthreads();
    if (tid < 16) blkcnt[blockIdx.x * 16 + tid] = sh_cnt[tid];
    if (tid < 8) atomicAdd(&stats[tid], sh_me[tid]);
    if (tid == 8) atomicAdd(&stats[8], sh_z);
}

// ---------------- scan + losses (expert bases padded to 64) ----------------
__global__ __launch_bounds__(256) void k_scan(const int* __restrict__ blkcnt,
                                              int* __restrict__ blkoff,
                                              int* __restrict__ meta,
                                              const float* __restrict__ stats,
                                              const int* __restrict__ flags,
                                              char* __restrict__ outc,
                                              int tailoff) {
    __shared__ int part[16][16];
    __shared__ int segbase[16][16];
    __shared__ int tot[16];
    int tid = threadIdx.x;
    int pair = tid & 15, seg = tid >> 4;
    int s = 0;
    for (int b = seg * 64; b < seg * 64 + 64; ++b) s += blkcnt[b * 16 + pair];
    part[seg][pair] = s;
    __syncthreads();
    if (tid < 16) {
        int run = 0;
        for (int g = 0; g < 16; ++g) { segbase[g][tid] = run; run += part[g][tid]; }
        tot[tid] = run;
    }
    __syncthreads();
    int run = segbase[seg][pair];
    for (int b = seg * 64; b < seg * 64 + 64; ++b) {
        blkoff[b * 16 + pair] = run;
        run += blkcnt[b * 16 + pair];
    }
    if (tid == 0) {
        int obf = flags[0];
        int basev = 0;
        float aux;
        if (obf) {
            float s_bf = 0.f;
            for (int e = 0; e < 8; ++e) {
                int t0 = tot[e], t1 = tot[8 + e];
                int k0 = t0 < CAP ? t0 : CAP;
                int k1 = t1 < CAP ? t1 : CAP;
                meta[e] = basev; meta[8 + e] = k0; meta[16 + e] = k0 + k1;
                basev += (k0 + k1 + 63) & ~63;   // 64-aligned regions
                float me_b = rnd_bf(stats[e] / (float)N_TOK);
                int cnt = t0 < 256 ? t0 : 256;
                float ce = (float)cnt * (1.f / 16384.f);
                s_bf = rnd_bf(s_bf + rnd_bf(me_b * ce));
            }
            aux = 8.f * s_bf;
        } else {
            float sf = 0.f;
            for (int e = 0; e < 8; ++e) {
                int t0 = tot[e], t1 = tot[8 + e];
                int k0 = t0 < CAP ? t0 : CAP;
                int k1 = t1 < CAP ? t1 : CAP;
                meta[e] = basev; meta[8 + e] = k0; meta[16 + e] = k0 + k1;
                basev += (k0 + k1 + 63) & ~63;   // 64-aligned regions
                sf += (stats[e] / (float)N_TOK) * ((float)t0 / (float)N_TOK);
            }
            aux = 8.f * sf;
        }
        float z = stats[8] / (float)(N_TOK * 8);
        if (obf) {
            ushort* tl = (ushort*)(outc + (size_t)tailoff * 2);
            tl[0] = f2bf(aux); tl[1] = f2bf(z);
        } else {
            float* tl = (float*)(outc + (size_t)tailoff * 4);
            tl[0] = aux; tl[1] = z;
        }
    }
}

// ---------------- build compact lists ----------------
__global__ __launch_bounds__(64) void k_build(const int* __restrict__ top2i,
                                              const int* __restrict__ blkoff,
                                              const int* __restrict__ meta,
                                              int* __restrict__ listtok) {
    __shared__ int sidx[32];
    int b = blockIdx.x, tid = threadIdx.x;
    if (tid < 32) sidx[tid] = top2i[b * 32 + tid];
    __syncthreads();
    if (tid < 16) {
        int t = b * 16 + tid;
        #pragma unroll
        for (int k = 0; k < 2; ++k) {
            int e = sidx[tid * 2 + k];
            int rank = 0;
            for (int i = 0; i < tid; ++i) if (sidx[i * 2 + k] == e) rank++;
            int pos = blkoff[b * 16 + k * 8 + e] + rank;
            if (pos < CAP) {
                int row = meta[e] + (k ? meta[8 + e] : 0) + pos;
                listtok[row] = t;
            }
        }
    }
}

// ---- convert+transpose: z%3: 0=Wg,1=Wu (CxH), 2=Wd (HxC) -> bf16 [Cc][R]; e = ebase + z/3 ----
__global__ __launch_bounds__(256) void k_transpose(const void* __restrict__ Wg,
                                                   const void* __restrict__ Wu,
                                                   const void* __restrict__ Wd,
                                                   ushort* __restrict__ tG,
                                                   ushort* __restrict__ tU,
                                                   ushort* __restrict__ tD,
                                                   const int* __restrict__ flags,
                                                   int ebase, int multi) {
    __shared__ ushort tile[32][33];
    int e = ebase + blockIdx.z / 3;
    int z = blockIdx.z % 3;
    int fbf = flags[2 + z];
    const void* src = (z == 0) ? Wg : ((z == 1) ? Wu : Wd);
    ushort* outp = (z == 0) ? tG : ((z == 1) ? tU : tD);
    size_t ooff = (size_t)(multi ? e : 0) * C_DIM * H_DIM;
    int R = (z == 2) ? H_DIM : C_DIM, Cc = (z == 2) ? C_DIM : H_DIM;
    size_t woff = (size_t)e * C_DIM * H_DIM;
    int c0 = blockIdx.x * 32, r0 = blockIdx.y * 32;
    if (c0 >= Cc || r0 >= R) return;
    int tx = threadIdx.x, ty = threadIdx.y;  // 32 x 8
    #pragma unroll
    for (int i = 0; i < 4; ++i) {
        int r = r0 + ty + i * 8, c = c0 + tx;
        ushort v = 0;
        if (r < R && c < Cc) {
            size_t idx = woff + (size_t)r * Cc + c;
            v = fbf ? ((const ushort*)src)[idx] : f2bf(((const float*)src)[idx]);
        }
        tile[ty + i * 8][tx] = v;
    }
    __syncthreads();
    #pragma unroll
    for (int i = 0; i < 4; ++i) {
        int c = c0 + ty + i * 8, r = r0 + tx;
        if (c < Cc && r < R) outp[ooff + (size_t)c * R + r] = tile[tx][ty + i * 8];
    }
}

// ---------------- fused gate+up GEMM ----------------
// gmode=1: row space is global (padded, expert from meta); gmode=0: expert-local (ex).
// m97 structure: global_load_lds width-16 staging, linear LDS (stride 32 bf16)
// with both-sides 16B XOR swizzle: slot = seg ^ ((row>>1)&3).
__global__ __launch_bounds__(256) void k_gateup(const ushort* __restrict__ xbf,
                                                const ushort* __restrict__ tG,
                                                const ushort* __restrict__ tU,
                                                const int* __restrict__ meta,
                                                const int* __restrict__ listtok,
                                                const int* __restrict__ flags,
                                                ushort* __restrict__ act,
                                                int gmode, int ex, int mbase) {
    int row0 = mbase + blockIdx.y * 64;        // global (gmode) or expert-local row
    int e, ml0;
    if (gmode) { e = expert_of(meta, row0); ml0 = row0 - meta[e]; }
    else       { e = ex;                     ml0 = row0; }
    int Me = meta[16 + e];
    if (ml0 >= Me) return;
    int ltb = meta[e];                          // listtok base for this expert
    size_t woff = (size_t)(gmode ? e : 0) * C_DIM * H_DIM;
    int h0 = blockIdx.x * 128;
    int fx = flags[0];
    int actrow0 = row0 - mbase;                 // chunk-local act row of block start

    __shared__ __align__(16) ushort sA[64 * 32];
    __shared__ __align__(16) ushort sG[128 * 32];
    __shared__ __align__(16) ushort sU[128 * 32];

    int tid = threadIdx.x;
    int lane = tid & 63, wv = tid >> 6;

    int sseg = (lane & 3) ^ ((lane >> 3) & 3);
    int ra = lane >> 2;

    // A: wave wv stages rows wv*16 .. wv*16+15 (gathered token rows, clamped)
    int arow = wv * 16 + ra;
    int qa = ml0 + arow; if (qa >= Me) qa = Me - 1;    // OOB -> dup last valid row
    const ushort* gA = xbf + (size_t)listtok[ltb + qa] * C_DIM + sseg * 8;
    ushort* lA = &sA[(wv * 16) * 32];

    // G/U: wave wv stages rows wv*32 .. wv*32+31 in two 16-row instructions
    int hr0 = h0 + wv * 32 + ra;
    int hc0 = hr0 < H_DIM ? hr0 : H_DIM - 1;
    int hc1 = (hr0 + 16) < H_DIM ? (hr0 + 16) : H_DIM - 1;
    const ushort* gG0 = tG + woff + (size_t)hc0 * C_DIM + sseg * 8;
    const ushort* gG1 = tG + woff + (size_t)hc1 * C_DIM + sseg * 8;
    const ushort* gU0 = tU + woff + (size_t)hc0 * C_DIM + sseg * 8;
    const ushort* gU1 = tU + woff + (size_t)hc1 * C_DIM + sseg * 8;
    ushort* lG = &sG[(wv * 32) * 32];
    ushort* lU = &sU[(wv * 32) * 32];

    int lrow = lane & 15, quad = lane >> 4;
    int rslot = (quad ^ ((lrow >> 1) & 3)) * 8;

    floatx4 zf = {0.f, 0.f, 0.f, 0.f};
    floatx4 accG[4][2], accU[4][2];
    #pragma unroll
    for (int i = 0; i < 4; ++i)
        #pragma unroll
        for (int j = 0; j < 2; ++j) { accG[i][j] = zf; accU[i][j] = zf; }

    for (int kk = 0; kk < C_DIM; kk += 32) {
        async16(gA + kk, lA);
        async16(gG0 + kk, lG);
        async16(gG1 + kk, lG + 16 * 32);
        async16(gU0 + kk, lU);
        async16(gU1 + kk, lU + 16 * 32);
        __syncthreads();
        short8 a[4], gfr[2], ufr[2];
        #pragma unroll
        for (int rt = 0; rt < 4; ++rt)
            a[rt] = *(const short8*)&sA[(rt * 16 + lrow) * 32 + rslot];
        #pragma unroll
        for (int j = 0; j < 2; ++j) {
            int n = wv * 32 + j * 16 + lrow;
            gfr[j] = *(const short8*)&sG[n * 32 + rslot];
            ufr[j] = *(const short8*)&sU[n * 32 + rslot];
        }
        #pragma unroll
        for (int rt = 0; rt < 4; ++rt)
            #pragma unroll
            for (int j = 0; j < 2; ++j) {
                accG[rt][j] = __builtin_amdgcn_mfma_f32_16x16x32_bf16(a[rt], gfr[j], accG[rt][j], 0, 0, 0);
                accU[rt][j] = __builtin_amdgcn_mfma_f32_16x16x32_bf16(a[rt], ufr[j], accU[rt][j], 0, 0, 0);
            }
        __syncthreads();
    }
    #pragma unroll
    for (int rt = 0; rt < 4; ++rt)
        #pragma unroll
        for (int j = 0; j < 2; ++j)
            #pragma unroll
            for (int r = 0; r < 4; ++r) {
                int ml = ml0 + rt * 16 + quad * 4 + r;
                int hh = h0 + wv * 32 + j * 16 + lrow;
                if (ml < Me && hh < H_DIM) {
                    float g = accG[rt][j][r];
                    float uu = accU[rt][j][r];
                    float res;
                    if (fx) {
                        float gb = rnd_bf(g), ub = rnd_bf(uu);
                        res = rnd_bf(gb / (1.f + __expf(-gb))) * ub;
                    } else {
                        res = (g / (1.f + __expf(-g))) * uu;
                    }
                    act[(size_t)(actrow0 + rt * 16 + quad * 4 + r) * H_DIM + hh] = f2bf(res);
                }
            }
}

// ---------------- down GEMM + scatter-combine ----------------
__global__ __launch_bounds__(256) void k_down(const ushort* __restrict__ act,
                                              const ushort* __restrict__ tD,
                                              const int* __restrict__ meta,
                                              const int* __restrict__ listtok,
                                              const float* __restrict__ top2v,
                                              const int* __restrict__ flags,
                                              char* __restrict__ outc,
                                              int gmode, int ex, int mbase) {
    int row0 = mbase + blockIdx.y * 64;
    int e, ml0;
    if (gmode) { e = expert_of(meta, row0); ml0 = row0 - meta[e]; }
    else       { e = ex;                     ml0 = row0; }
    int Me = meta[16 + e];
    if (ml0 >= Me) return;
    int ltb = meta[e];
    int k0cnt = meta[8 + e];
    size_t woff = (size_t)(gmode ? e : 0) * C_DIM * H_DIM;
    int c0 = blockIdx.x * 128;
    int obf = flags[0];
    int actrow0 = row0 - mbase;

    __shared__ __align__(16) ushort sA[64 * 32];
    __shared__ __align__(16) ushort sB[128 * 32];

    int tid = threadIdx.x;
    int lane = tid & 63, wv = tid >> 6;

    int sseg = (lane & 3) ^ ((lane >> 3) & 3);
    int ra = lane >> 2;

    // A rows: chunk-local act rows (padding rows hold garbage; masked at write)
    const ushort* gA = act + (size_t)(actrow0 + wv * 16 + ra) * H_DIM + sseg * 8;
    ushort* lA = &sA[(wv * 16) * 32];

    const ushort* gB0 = tD + woff + (size_t)(c0 + wv * 32 + ra) * H_DIM + sseg * 8;
    const ushort* gB1 = tD + woff + (size_t)(c0 + wv * 32 + 16 + ra) * H_DIM + sseg * 8;
    ushort* lB = &sB[(wv * 32) * 32];

    int lrow = lane & 15, quad = lane >> 4;
    int rslot = (quad ^ ((lrow >> 1) & 3)) * 8;

    floatx4 zf = {0.f, 0.f, 0.f, 0.f};
    floatx4 acc[4][2];
    #pragma unroll
    for (int i = 0; i < 4; ++i)
        #pragma unroll
        for (int j = 0; j < 2; ++j) acc[i][j] = zf;

    for (int kk = 0; kk < H_DIM; kk += 32) {
        async16(gA + kk, lA);
        async16(gB0 + kk, lB);
        async16(gB1 + kk, lB + 16 * 32);
        __syncthreads();
        short8 a[4], b[2];
        #pragma unroll
        for (int rt = 0; rt < 4; ++rt)
            a[rt] = *(const short8*)&sA[(rt * 16 + lrow) * 32 + rslot];
        #pragma unroll
        for (int j = 0; j < 2; ++j)
            b[j] = *(const short8*)&sB[(wv * 32 + j * 16 + lrow) * 32 + rslot];
        #pragma unroll
        for (int rt = 0; rt < 4; ++rt)
            #pragma unroll
            for (int j = 0; j < 2; ++j)
                acc[rt][j] = __builtin_amdgcn_mfma_f32_16x16x32_bf16(a[rt], b[j], acc[rt][j], 0, 0, 0);
        __syncthreads();
    }
    #pragma unroll
    for (int rt = 0; rt < 4; ++rt)
        #pragma unroll
        for (int j = 0; j < 2; ++j)
            #pragma unroll
            for (int r = 0; r < 4; ++r) {
                int ml = ml0 + rt * 16 + quad * 4 + r;   // expert-local row
                if (ml < Me) {
                    int t = listtok[ltb + ml];
                    int k = (ml >= k0cnt) ? 1 : 0;
                    float w = top2v[t * 2 + k];
                    int cc = c0 + wv * 32 + j * 16 + lrow;
                    float y = acc[rt][j][r];
                    size_t oidx = (size_t)t * C_DIM + cc;
                    if (obf) {
                        ushort contrib = f2bf(w * rnd_bf(y));
                        uint32_t* word = (uint32_t*)outc + (oidx >> 1);
                        int hi = (int)(oidx & 1);
                        uint32_t old = *word, assumed;
                        do {
                            assumed = old;
                            ushort cur = hi ? (ushort)(assumed >> 16) : (ushort)(assumed & 0xFFFFu);
                            ushort nw = f2bf(bf2f(cur) + bf2f(contrib));
                            uint32_t repl = hi ? ((assumed & 0xFFFFu) | ((uint32_t)nw << 16))
                                               : ((assumed & 0xFFFF0000u) | (uint32_t)nw);
                            if (repl == assumed) break;
                            old = atomicCAS(word, assumed, repl);
                        } while (old != assumed);
                    } else {
                        atomicAdd((float*)outc + oidx, w * y);
                    }
                }
            }
}

extern "C" void kernel_launch(void* const* d_in, const int* in_sizes, int n_in,
                              void* d_out, int out_size, void* d_ws, size_t ws_size,
                              hipStream_t stream) {
    const void* x  = d_in[0];
    const void* gw = d_in[1];
    const void* Wg = d_in[2];
    const void* Wu = d_in[3];
    const void* Wd = d_in[4];
    char* outc = (char*)d_out;

    char* ws = (char*)d_ws;
    size_t off = 0;
    auto alloc = [&](size_t bytes) -> char* {
        char* p = ws + off;
        off += (bytes + 255) & ~(size_t)255;
        return p;
    };
    int*    flags   = (int*)alloc(64);
    float*  stats   = (float*)alloc(64);
    int*    top2i   = (int*)alloc((size_t)N_TOK * 2 * 4);
    float*  top2v   = (float*)alloc((size_t)N_TOK * 2 * 4);
    int*    blkcnt  = (int*)alloc((size_t)NB0 * 16 * 4);
    int*    blkoff  = (int*)alloc((size_t)NB0 * 16 * 4);
    int*    meta    = (int*)alloc(256);
    int*    listtok = (int*)alloc((size_t)GTOT * 4);
    ushort* xbf     = (ushort*)alloc((size_t)N_TOK * C_DIM * 2);

    size_t Wset  = (size_t)C_DIM * H_DIM * 2;          // one expert, one matrix (bf16)
    size_t Wfast = Wset * E_NUM;                        // all experts
    size_t rowB  = (size_t)H_DIM * 2;

    // fast path: all-expert weights resident + global-row act chunking
    bool fast = false;
    int CH = 0;
    {
        size_t fixed = off + 3 * Wfast;
        if (ws_size > fixed + (1 << 20)) {
            size_t avail = ws_size - fixed - (1 << 20);
            size_t ch = avail / rowB;
            if (ch > (size_t)GTOT) ch = GTOT;
            ch &= ~(size_t)63;
            if (ch >= 8192) { fast = true; CH = (int)ch; }
        }
    }

    // common prologue
    k_sniff<<<1, 256, 0, stream>>>((const uint32_t*)x, (const uint32_t*)gw,
                                   (const uint32_t*)Wg, (const uint32_t*)Wu,
                                   (const uint32_t*)Wd, flags);
    k_zero<<<2048, 256, 0, stream>>>((uint32_t*)d_out, flags, stats, out_size);
    k_xcast<<<2048, 256, 0, stream>>>(x, flags, xbf);
    k_gate<<<NB0, 256, 0, stream>>>(x, gw, flags, top2i, top2v, blkcnt, stats);
    k_scan<<<1, 256, 0, stream>>>(blkcnt, blkoff, meta, stats, flags, outc, out_size - 2);
    k_build<<<NB0, 64, 0, stream>>>(top2i, blkoff, meta, listtok);

    dim3 tb(32, 8);
    if (fast) {
        ushort* tG  = (ushort*)alloc(Wfast);
        ushort* tU  = (ushort*)alloc(Wfast);
        ushort* tD  = (ushort*)alloc(Wfast);
        ushort* act = (ushort*)alloc((size_t)CH * rowB);
        int nch = (GTOT + CH - 1) / CH;

        // transpose all experts in one launch
        k_transpose<<<dim3(86, 86, 24), tb, 0, stream>>>(Wg, Wu, Wd, tG, tU, tD, flags, 0, 1);
        for (int c = 0; c < nch; ++c) {
            k_gateup<<<dim3((H_DIM + 127) / 128, CH / 64), 256, 0, stream>>>(
                xbf, tG, tU, meta, listtok, flags, act, 1, 0, c * CH);
            k_down<<<dim3(C_DIM / 128, CH / 64), 256, 0, stream>>>(
                act, tD, meta, listtok, top2v, flags, outc, 1, 0, c * CH);
        }
    } else {
        // legacy per-expert path (round-1 behavior)
        ushort* tG = (ushort*)alloc(Wset);
        ushort* tU = (ushort*)alloc(Wset);
        ushort* tD = (ushort*)alloc(Wset);
        size_t avail = (ws_size > off + (1 << 20)) ? (ws_size - off - (1 << 20)) : rowB * 64;
        int CHl = (int)(avail / rowB);
        if (CHl > 2 * CAP) CHl = 2 * CAP;
        CHl &= ~63;
        if (CHl < 64) CHl = 64;
        int nch = (2 * CAP + CHl - 1) / CHl;
        ushort* act = (ushort*)alloc((size_t)CHl * rowB);

        for (int e = 0; e < E_NUM; ++e) {
            k_transpose<<<dim3(86, 86, 3), tb, 0, stream>>>(Wg, Wu, Wd, tG, tU, tD, flags, e, 0);
            for (int c = 0; c < nch; ++c) {
                k_gateup<<<dim3((H_DIM + 127) / 128, CHl / 64), 256, 0, stream>>>(
                    xbf, tG, tU, meta, listtok, flags, act, 0, e, c * CHl);
                k_down<<<dim3(C_DIM / 128, CHl / 64), 256, 0, stream>>>(
                    act, tD, meta, listtok, top2v, flags, outc, 0, e, c * CHl);
            }
        }
    }
}